// Round 3
// baseline (960.244 us; speedup 1.0000x reference)
//
#include <hip/hip_runtime.h>

__device__ __forceinline__ float sigmoidf_(float x) {
    return 1.0f / (1.0f + __expf(-x));
}
__device__ __forceinline__ float tanhf_(float x) {
    return 1.0f - 2.0f / (1.0f + __expf(2.0f * x));
}

// ---------------------------------------------------------------------------
// Packed weights, unit-padded 100 -> 128, gates interleaved as float4 [r,z,n,0]:
//  gioq[o][u] = {gr, gz, gin, bhn}   gr = b_ih[u]+b_hh[u]+obs.W_ih[u,:100], etc.
//  Whq [k][u] = {W_hh[u][k], W_hh[100+u][k], W_hh[200+u][k], 0}   k<100
//  Wxq [k][u] = {W_ih[u][100+k], W_ih[100+u][100+k], W_ih[200+u][100+k], 0} k<18
// ---------------------------------------------------------------------------
__global__ __launch_bounds__(64) void precompute_kernel(
    const float* __restrict__ obs, const float* __restrict__ W_ih,
    const float* __restrict__ W_hh, const float* __restrict__ b_ih,
    const float* __restrict__ b_hh, const float* __restrict__ W1,
    const float* __restrict__ W2,
    float4* __restrict__ gioq, float4* __restrict__ Wxq,
    float4* __restrict__ Whq, float* __restrict__ W1T, float* __restrict__ W2T)
{
    int t = blockIdx.x * 64 + threadIdx.x;
    if (t < 8192) { // gioq
        int o = t >> 7, u = t & 127;
        float4 r = {0.f, 0.f, 0.f, 0.f};
        if (u < 100) {
            float a0 = b_ih[u] + b_hh[u];
            float a1 = b_ih[100 + u] + b_hh[100 + u];
            float a2 = b_ih[200 + u];
            const float* orow = obs + o * 100;
            const float* w0 = W_ih + (size_t)u * 118;
            const float* w1 = W_ih + (size_t)(100 + u) * 118;
            const float* w2 = W_ih + (size_t)(200 + u) * 118;
            for (int k = 0; k < 100; ++k) {
                float ov = orow[k];
                a0 = fmaf(ov, w0[k], a0);
                a1 = fmaf(ov, w1[k], a1);
                a2 = fmaf(ov, w2[k], a2);
            }
            r.x = a0; r.y = a1; r.z = a2; r.w = b_hh[200 + u];
        }
        gioq[t] = r; return;
    }
    t -= 8192;
    if (t < 12800) { // Whq
        int k = t >> 7, u = t & 127;
        float4 r = {0.f, 0.f, 0.f, 0.f};
        if (u < 100) {
            r.x = W_hh[(size_t)u * 100 + k];
            r.y = W_hh[(size_t)(100 + u) * 100 + k];
            r.z = W_hh[(size_t)(200 + u) * 100 + k];
        }
        Whq[t] = r; return;
    }
    t -= 12800;
    if (t < 2304) { // Wxq
        int k = t >> 7, u = t & 127;
        float4 r = {0.f, 0.f, 0.f, 0.f};
        if (u < 100) {
            r.x = W_ih[(size_t)u * 118 + 100 + k];
            r.y = W_ih[(size_t)(100 + u) * 118 + 100 + k];
            r.z = W_ih[(size_t)(200 + u) * 118 + 100 + k];
        }
        Wxq[t] = r; return;
    }
    t -= 2304;
    if (t < 5000) { int g = t / 50, j = t % 50; W1T[t] = W1[j * 100 + g]; return; }
    t -= 5000;
    if (t < 1250) { int j = t / 25, i = t % 25; W2T[t] = W2[i * 50 + j]; }
}

// ---------------------------------------------------------------------------
// GRU level. Block = 256 thr (4 waves) = 32 cells; wave = 8 cells;
// lane = unit u1=lane (+u2=64+lane for lane<36, zero-padded weights).
// x and h_child staged in LDS, read as wave-uniform broadcasts.
// Weights read per-lane coalesced float4 (L1-resident stream).
// Pair-sum for next level done in-register (lane owns both siblings).
// h layout: [cell][100] row-major.
// ---------------------------------------------------------------------------
template<bool HASH>
__global__ __launch_bounds__(256, 4) void gru_level(
    const float4* __restrict__ gioq,  // [64][128]
    const float4* __restrict__ Wxq,   // [18][128]
    const float4* __restrict__ Whq,   // [100][128]
    const float* __restrict__ samp,   // (O,P,63,8)
    const float* __restrict__ addr,   // (O,P,63,10)
    const float* __restrict__ hin,    // [cells][100]
    float* __restrict__ hout,         // [cells/2][100] pairsum, or [cells][100] if last
    int lw, int last)
{
    __shared__ float xs[32 * 18];
    __shared__ float hch[32 * 100];

    const int tid = threadIdx.x;
    const int c0 = blockIdx.x * 32;
    const int w = 1 << lw;

    // stage x tile (coalesced-ish)
    for (int f = tid; f < 576; f += 256) {
        int cl = f / 18, j = f - cl * 18;
        int c = c0 + cl;
        int op = c >> lw, node = w - 1 + (c & (w - 1));
        size_t nb = (size_t)(op * 63 + node);
        xs[f] = (j < 8) ? samp[nb * 8 + j] : addr[nb * 10 + (j - 8)];
    }
    // stage h_child tile (fully coalesced, rows contiguous)
    if (HASH) {
        const float* hsrc = hin + (size_t)c0 * 100;
        for (int f = tid; f < 3200; f += 256) hch[f] = hsrc[f];
    }
    __syncthreads();

    const int lane = tid & 63;
    const int ty = tid >> 6;
    const int cb = ty * 8;                 // wave's first local cell
    const int o = c0 >> (lw + 6);          // wave-uniform
    const bool two = lane < 36;
    const int u1 = lane, u2 = 64 + lane;

    const float4 g1 = gioq[o * 128 + u1];
    const float4 g2 = gioq[o * 128 + u2];  // zero-padded for u>=100

    float A1[8], B1[8], C1[8], A2[8], B2[8], C2[8];
    #pragma unroll
    for (int i = 0; i < 8; ++i) {
        A1[i] = g1.x; B1[i] = g1.y; C1[i] = g1.z;
        A2[i] = g2.x; B2[i] = g2.y; C2[i] = g2.z;
    }

    // ---- input loop (k < 18): accumulate r, z, i_n ----
    #pragma unroll
    for (int k = 0; k < 18; ++k) {
        const float4 w1 = Wxq[k * 128 + u1];
        const float4 w2 = Wxq[k * 128 + u2];
        #pragma unroll
        for (int i = 0; i < 8; ++i) {
            float xk = xs[(cb + i) * 18 + k];      // LDS broadcast
            A1[i] = fmaf(xk, w1.x, A1[i]); B1[i] = fmaf(xk, w1.y, B1[i]); C1[i] = fmaf(xk, w1.z, C1[i]);
            A2[i] = fmaf(xk, w2.x, A2[i]); B2[i] = fmaf(xk, w2.y, B2[i]); C2[i] = fmaf(xk, w2.z, C2[i]);
        }
    }

    // ---- hidden loop (k < 100): accumulate r, z, h_n ----
    float D1[8], D2[8];
    #pragma unroll
    for (int i = 0; i < 8; ++i) { D1[i] = g1.w; D2[i] = g2.w; }
    if (HASH) {
        #pragma unroll 2
        for (int k = 0; k < 100; ++k) {
            const float4 w1 = Whq[k * 128 + u1];
            const float4 w2 = Whq[k * 128 + u2];
            #pragma unroll
            for (int i = 0; i < 8; ++i) {
                float hk = hch[(cb + i) * 100 + k];  // LDS broadcast
                A1[i] = fmaf(hk, w1.x, A1[i]); B1[i] = fmaf(hk, w1.y, B1[i]); D1[i] = fmaf(hk, w1.z, D1[i]);
                A2[i] = fmaf(hk, w2.x, A2[i]); B2[i] = fmaf(hk, w2.y, B2[i]); D2[i] = fmaf(hk, w2.z, D2[i]);
            }
        }
    }

    // ---- epilogue: gates + new h ----
    float h1[8], h2[8];
    #pragma unroll
    for (int i = 0; i < 8; ++i) {
        float hc1 = 0.f, hc2 = 0.f;
        if (HASH) {
            hc1 = hch[(cb + i) * 100 + u1];
            hc2 = two ? hch[(cb + i) * 100 + u2] : 0.f;
        }
        float r1 = sigmoidf_(A1[i]), z1 = sigmoidf_(B1[i]);
        float n1 = tanhf_(C1[i] + r1 * D1[i]);
        h1[i] = (1.f - z1) * n1 + z1 * hc1;
        float r2 = sigmoidf_(A2[i]), z2 = sigmoidf_(B2[i]);
        float n2 = tanhf_(C2[i] + r2 * D2[i]);
        h2[i] = (1.f - z2) * n2 + z2 * hc2;
    }

    if (!last) { // pair-sum: lane owns both siblings -> register add, coalesced store
        #pragma unroll
        for (int j = 0; j < 4; ++j) {
            size_t row = (size_t)((c0 >> 1) + (cb >> 1) + j);
            hout[row * 100 + u1] = h1[2 * j] + h1[2 * j + 1];
            if (two) hout[row * 100 + u2] = h2[2 * j] + h2[2 * j + 1];
        }
    } else {
        #pragma unroll
        for (int i = 0; i < 8; ++i) {
            size_t row = (size_t)(c0 + cb + i);
            hout[row * 100 + u1] = h1[i];
            if (two) hout[row * 100 + u2] = h2[i];
        }
    }
}

// ---------------------------------------------------------------------------
// MLP head + logsumexp over the 64 particles. Block = one o; lane = particle.
// Root h is [4096][100]; staged via LDS (pad 101) for conflict-free reads.
// ---------------------------------------------------------------------------
__global__ __launch_bounds__(64) void mlp_lse(
    const float* __restrict__ h0,   // [4096][100]
    const float* __restrict__ W1T,  // [100][50]
    const float* __restrict__ b1,
    const float* __restrict__ W2T,  // [50][25]
    const float* __restrict__ b2,
    const float* __restrict__ W3,
    const float* __restrict__ b3,
    float* __restrict__ out)
{
    __shared__ float hs[64 * 101];
    const int o = blockIdx.x;
    const int p = threadIdx.x;
    const float* src = h0 + (size_t)o * 64 * 100;
    for (int f = p; f < 6400; f += 64) {
        int cl = f / 100, g = f - cl * 100;
        hs[cl * 101 + g] = src[f];
    }
    __syncthreads();

    float y1[50];
    #pragma unroll
    for (int j = 0; j < 50; ++j) y1[j] = b1[j];
    #pragma unroll 2
    for (int g = 0; g < 100; ++g) {
        float rg = hs[p * 101 + g];
        const float* wr = W1T + g * 50;
        #pragma unroll
        for (int j = 0; j < 50; ++j) y1[j] = fmaf(rg, wr[j], y1[j]);
    }

    float y2[25];
    #pragma unroll
    for (int i = 0; i < 25; ++i) y2[i] = b2[i];
    #pragma unroll
    for (int j = 0; j < 50; ++j) {
        float v = fmaxf(y1[j], 0.0f);
        const float* wr = W2T + j * 25;
        #pragma unroll
        for (int i = 0; i < 25; ++i) y2[i] = fmaf(v, wr[i], y2[i]);
    }

    float cv = b3[0];
    #pragma unroll
    for (int i = 0; i < 25; ++i) cv = fmaf(fmaxf(y2[i], 0.0f), W3[i], cv);

    float m = cv;
    #pragma unroll
    for (int s = 1; s < 64; s <<= 1) m = fmaxf(m, __shfl_xor(m, s));
    float e = __expf(cv - m);
    #pragma unroll
    for (int s = 1; s < 64; s <<= 1) e += __shfl_xor(e, s);
    if (p == 0) out[o] = m + __logf(e) - 4.1588830833596715f; // log(64)
}

// ---------------------------------------------------------------------------
extern "C" void kernel_launch(void* const* d_in, const int* in_sizes, int n_in,
                              void* d_out, int out_size, void* d_ws, size_t ws_size,
                              hipStream_t stream)
{
    const float* obs  = (const float*)d_in[0];
    const float* samp = (const float*)d_in[1];
    const float* addr = (const float*)d_in[2];
    const float* W_ih = (const float*)d_in[3];
    const float* W_hh = (const float*)d_in[4];
    const float* b_ih = (const float*)d_in[5];
    const float* b_hh = (const float*)d_in[6];
    const float* W1   = (const float*)d_in[7];
    const float* b1   = (const float*)d_in[8];
    const float* W2   = (const float*)d_in[9];
    const float* b2   = (const float*)d_in[10];
    const float* W3   = (const float*)d_in[11];
    const float* b3   = (const float*)d_in[12];
    float* out = (float*)d_out;

    float* ws = (float*)d_ws;
    float4* gioq = (float4*)(ws);            // 8192  f4 =  32768 f
    float4* Wxq  = (float4*)(ws + 32768);    // 2304  f4 =   9216 f
    float4* Whq  = (float4*)(ws + 41984);    // 12800 f4 =  51200 f
    float*  W1T  = ws + 93184;               // 5000
    float*  W2T  = ws + 98184;               // 1250
    float*  hA   = ws + 102400;              // 65536*100 = 6,553,600
    float*  hB   = hA + 6553600;             // 32768*100 = 3,276,800

    precompute_kernel<<<(29546 + 63) / 64, 64, 0, stream>>>(
        obs, W_ih, W_hh, b_ih, b_hh, W1, W2, gioq, Wxq, Whq, W1T, W2T);

    // leaf level (lw=5): h_child = 0, pairsum -> hA [65536][100]
    gru_level<false><<<4096, 256, 0, stream>>>(gioq, Wxq, Whq, samp, addr,
                                               nullptr, hA, 5, 0);
    // L4: hA -> hB [32768][100]
    gru_level<true><<<2048, 256, 0, stream>>>(gioq, Wxq, Whq, samp, addr, hA, hB, 4, 0);
    // L3: hB -> hA [16384][100]
    gru_level<true><<<1024, 256, 0, stream>>>(gioq, Wxq, Whq, samp, addr, hB, hA, 3, 0);
    // L2: hA -> hB [8192][100]
    gru_level<true><<<512, 256, 0, stream>>>(gioq, Wxq, Whq, samp, addr, hA, hB, 2, 0);
    // L1: hB -> hA [4096][100]
    gru_level<true><<<256, 256, 0, stream>>>(gioq, Wxq, Whq, samp, addr, hB, hA, 1, 0);
    // L0 (root, last): hA -> hB [4096][100]
    gru_level<true><<<128, 256, 0, stream>>>(gioq, Wxq, Whq, samp, addr, hA, hB, 0, 1);

    mlp_lse<<<64, 64, 0, stream>>>(hB, W1T, b1, W2T, b2, W3, b3, out);
}

// Round 4
// 750.971 us; speedup vs baseline: 1.2787x; 1.2787x over previous
//
#include <hip/hip_runtime.h>

__device__ __forceinline__ float sigmoidf_(float x) {
    return 1.0f / (1.0f + __expf(-x));
}
__device__ __forceinline__ float tanhf_(float x) {
    return 1.0f - 2.0f / (1.0f + __expf(2.0f * x));
}

// ---------------------------------------------------------------------------
// Packed weights (units padded 100 -> 104). Per unit u, 3 gate rows g=0(r),1(z),2(n):
//  gio4[(o*104+u)*4 + {0,1,2,3}] = {gr, gz, gc, gd}
//    gr = b_ih[u]     + b_hh[u]     + obs[o].W_ih[u,     :100]
//    gz = b_ih[100+u] + b_hh[100+u] + obs[o].W_ih[100+u, :100]
//    gc = b_ih[200+u]               + obs[o].W_ih[200+u, :100]   (input part of n)
//    gd = b_hh[200+u]                                            (hidden part of n)
//  Wh3[k*312 + u*3 + g] = W_hh[(g*100+u)][k]          k<100  (0 for u>=100)
//  Wx3[k*312 + u*3 + g] = W_ih[(g*100+u)][100+k]      k<18   (0 for u>=100)
// ---------------------------------------------------------------------------
__global__ __launch_bounds__(64) void precompute_kernel(
    const float* __restrict__ obs, const float* __restrict__ W_ih,
    const float* __restrict__ W_hh, const float* __restrict__ b_ih,
    const float* __restrict__ b_hh, const float* __restrict__ W1,
    const float* __restrict__ W2,
    float* __restrict__ gio4, float* __restrict__ Wh3,
    float* __restrict__ Wx3, float* __restrict__ W1T, float* __restrict__ W2T)
{
    int t = blockIdx.x * 64 + threadIdx.x;
    if (t < 6656) { // gio4
        int o = t / 104, u = t % 104;
        float4 r = {0.f, 0.f, 0.f, 0.f};
        if (u < 100) {
            float a0 = b_ih[u] + b_hh[u];
            float a1 = b_ih[100 + u] + b_hh[100 + u];
            float a2 = b_ih[200 + u];
            const float* orow = obs + o * 100;
            const float* w0 = W_ih + (size_t)u * 118;
            const float* w1 = W_ih + (size_t)(100 + u) * 118;
            const float* w2 = W_ih + (size_t)(200 + u) * 118;
            for (int k = 0; k < 100; ++k) {
                float ov = orow[k];
                a0 = fmaf(ov, w0[k], a0);
                a1 = fmaf(ov, w1[k], a1);
                a2 = fmaf(ov, w2[k], a2);
            }
            r.x = a0; r.y = a1; r.z = a2; r.w = b_hh[200 + u];
        }
        ((float4*)gio4)[t] = r;
        return;
    }
    t -= 6656;
    if (t < 31200) { // Wh3
        int k = t / 312, rr = t % 312, u = rr / 3, g = rr % 3;
        Wh3[t] = (u < 100) ? W_hh[(size_t)(g * 100 + u) * 100 + k] : 0.f;
        return;
    }
    t -= 31200;
    if (t < 5616) { // Wx3
        int k = t / 312, rr = t % 312, u = rr / 3, g = rr % 3;
        Wx3[t] = (u < 100) ? W_ih[(size_t)(g * 100 + u) * 118 + 100 + k] : 0.f;
        return;
    }
    t -= 5616;
    if (t < 5000) { int g = t / 50, j = t % 50; W1T[t] = W1[j * 100 + g]; return; }
    t -= 5000;
    if (t < 1250) { int j = t / 25, i = t % 25; W2T[t] = W2[i * 50 + j]; }
}

// ---------------------------------------------------------------------------
// One tree level. Block = 512 threads = 8 waves over the SAME 64 cells
// (lane = cell). Wave w computes units [w*13, w*13+13) (104 padded units).
// Weights are wave-uniform -> scalar loads (SGPR broadcast); h_k comes from
// a per-block LDS tile (stride 101 -> conflict-free); x lives in registers
// (statically unrolled). Pair-sum for the next level via __shfl_xor.
// h layout: [cell][100] row-major.
// ---------------------------------------------------------------------------
template<bool HASH>
__global__ __launch_bounds__(512) void gru_level(
    const float* __restrict__ gio4,  // [64][104][4]
    const float* __restrict__ Wx3,   // [18][312]
    const float* __restrict__ Wh3,   // [100][312]
    const float* __restrict__ samp,  // (O,P,63,8)
    const float* __restrict__ addr,  // (O,P,63,10)
    const float* __restrict__ hin,   // [cells][100]
    float* __restrict__ hout,        // [cells/2][100] pairsum, or [cells][100] if last
    int lw, int last)
{
    extern __shared__ float hch[];   // [64][101] when HASH

    const int tid = threadIdx.x;
    const int lane = tid & 63;
    const int c0 = blockIdx.x * 64;
    const int c = c0 + lane;
    const int w = 1 << lw;

    if constexpr (HASH) {
        const float* hsrc = hin + (size_t)c0 * 100;
        for (int f = tid; f < 6400; f += 512) {
            int cl = f / 100, g = f - cl * 100;
            hch[cl * 101 + g] = hsrc[f];
        }
        __syncthreads();
    }

    // wave-uniform unit base (readfirstlane makes uniformity provable -> s_loads)
    const int ub = __builtin_amdgcn_readfirstlane((tid >> 6) * 13);
    const int o = c0 >> (lw + 6);    // blockIdx-derived -> uniform

    // ---- x into registers (static unroll; no runtime-indexed array) ----
    const int op = c >> lw;
    const int node = w - 1 + (c & (w - 1));
    const size_t nb = (size_t)(op * 63 + node);
    float x[18];
    {
        const float4* sp4 = (const float4*)(samp + nb * 8);   // 32B-aligned
        float4 s0 = sp4[0], s1 = sp4[1];
        x[0] = s0.x; x[1] = s0.y; x[2] = s0.z; x[3] = s0.w;
        x[4] = s1.x; x[5] = s1.y; x[6] = s1.z; x[7] = s1.w;
        const float2* ap2 = (const float2*)(addr + nb * 10);  // 8B-aligned
        #pragma unroll
        for (int q = 0; q < 5; ++q) { float2 a = ap2[q]; x[8 + 2 * q] = a.x; x[9 + 2 * q] = a.y; }
    }

    // ---- init accumulators from gio4 (uniform s_loads) ----
    const float4* gb = (const float4*)(gio4 + ((size_t)o * 104 + ub) * 4);
    float aR[13], aZ[13], aC[13], aD[13];
    #pragma unroll
    for (int j = 0; j < 13; ++j) {
        float4 g = gb[j];
        aR[j] = g.x; aZ[j] = g.y; aC[j] = g.z; aD[j] = g.w;
    }

    // ---- input loop (k<18, fully unrolled): accumulate r, z, i_n ----
    #pragma unroll
    for (int k = 0; k < 18; ++k) {
        const float* wk = Wx3 + k * 312 + ub * 3;
        float xk = x[k];
        #pragma unroll
        for (int j = 0; j < 13; ++j) {
            aR[j] = fmaf(xk, wk[j * 3 + 0], aR[j]);
            aZ[j] = fmaf(xk, wk[j * 3 + 1], aZ[j]);
            aC[j] = fmaf(xk, wk[j * 3 + 2], aC[j]);
        }
    }

    // ---- hidden loop (k<100): accumulate r, z, h_n ----
    if constexpr (HASH) {
        #pragma unroll 2
        for (int k = 0; k < 100; ++k) {
            float hk = hch[lane * 101 + k];
            const float* wk = Wh3 + k * 312 + ub * 3;
            #pragma unroll
            for (int j = 0; j < 13; ++j) {
                aR[j] = fmaf(hk, wk[j * 3 + 0], aR[j]);
                aZ[j] = fmaf(hk, wk[j * 3 + 1], aZ[j]);
                aD[j] = fmaf(hk, wk[j * 3 + 2], aD[j]);
            }
        }
    }

    // ---- epilogue: gates, new h, pair-sum, store ----
    const int halfrow = (c >> 1) * 100;
    #pragma unroll
    for (int j = 0; j < 13; ++j) {
        int u = ub + j;                       // scalar
        float r = sigmoidf_(aR[j]);
        float z = sigmoidf_(aZ[j]);
        float n = tanhf_(aC[j] + r * aD[j]);
        float hc = 0.f;
        if constexpr (HASH) hc = hch[lane * 101 + u];
        float hv = (1.f - z) * n + z * hc;
        if (last) {
            if (u < 100) hout[(size_t)c * 100 + u] = hv;
        } else {
            float hs = hv + __shfl_xor(hv, 1);
            if (u < 100 && (lane & 1) == 0) hout[(size_t)halfrow + u] = hs;
        }
    }
}

// ---------------------------------------------------------------------------
// MLP head + logsumexp over the 64 particles. Block = one o; lane = particle.
// ---------------------------------------------------------------------------
__global__ __launch_bounds__(64) void mlp_lse(
    const float* __restrict__ h0,   // [4096][100]
    const float* __restrict__ W1T,  // [100][50]
    const float* __restrict__ b1,
    const float* __restrict__ W2T,  // [50][25]
    const float* __restrict__ b2,
    const float* __restrict__ W3,
    const float* __restrict__ b3,
    float* __restrict__ out)
{
    __shared__ float hs[64 * 101];
    const int o = blockIdx.x;
    const int p = threadIdx.x;
    const float* src = h0 + (size_t)o * 64 * 100;
    for (int f = p; f < 6400; f += 64) {
        int cl = f / 100, g = f - cl * 100;
        hs[cl * 101 + g] = src[f];
    }
    __syncthreads();

    float y1[50];
    #pragma unroll
    for (int j = 0; j < 50; ++j) y1[j] = b1[j];
    #pragma unroll 2
    for (int g = 0; g < 100; ++g) {
        float rg = hs[p * 101 + g];
        const float* wr = W1T + g * 50;
        #pragma unroll
        for (int j = 0; j < 50; ++j) y1[j] = fmaf(rg, wr[j], y1[j]);
    }

    float y2[25];
    #pragma unroll
    for (int i = 0; i < 25; ++i) y2[i] = b2[i];
    #pragma unroll
    for (int j = 0; j < 50; ++j) {
        float v = fmaxf(y1[j], 0.0f);
        const float* wr = W2T + j * 25;
        #pragma unroll
        for (int i = 0; i < 25; ++i) y2[i] = fmaf(v, wr[i], y2[i]);
    }

    float cv = b3[0];
    #pragma unroll
    for (int i = 0; i < 25; ++i) cv = fmaf(fmaxf(y2[i], 0.0f), W3[i], cv);

    float m = cv;
    #pragma unroll
    for (int s = 1; s < 64; s <<= 1) m = fmaxf(m, __shfl_xor(m, s));
    float e = __expf(cv - m);
    #pragma unroll
    for (int s = 1; s < 64; s <<= 1) e += __shfl_xor(e, s);
    if (p == 0) out[o] = m + __logf(e) - 4.1588830833596715f; // log(64)
}

// ---------------------------------------------------------------------------
extern "C" void kernel_launch(void* const* d_in, const int* in_sizes, int n_in,
                              void* d_out, int out_size, void* d_ws, size_t ws_size,
                              hipStream_t stream)
{
    const float* obs  = (const float*)d_in[0];
    const float* samp = (const float*)d_in[1];
    const float* addr = (const float*)d_in[2];
    const float* W_ih = (const float*)d_in[3];
    const float* W_hh = (const float*)d_in[4];
    const float* b_ih = (const float*)d_in[5];
    const float* b_hh = (const float*)d_in[6];
    const float* W1   = (const float*)d_in[7];
    const float* b1   = (const float*)d_in[8];
    const float* W2   = (const float*)d_in[9];
    const float* b2   = (const float*)d_in[10];
    const float* W3   = (const float*)d_in[11];
    const float* b3   = (const float*)d_in[12];
    float* out = (float*)d_out;

    float* ws   = (float*)d_ws;
    float* gio4 = ws;               // 26624 floats
    float* Wh3  = ws + 26624;       // 31200
    float* Wx3  = ws + 57824;       // 5616
    float* W1T  = ws + 63440;       // 5000
    float* W2T  = ws + 68440;       // 1250
    float* hA   = ws + 69696;       // 65536*100 = 6,553,600
    float* hB   = hA + 6553600;     // 32768*100 = 3,276,800

    precompute_kernel<<<(49722 + 63) / 64, 64, 0, stream>>>(
        obs, W_ih, W_hh, b_ih, b_hh, W1, W2, gio4, Wh3, Wx3, W1T, W2T);

    const int LDSB = 64 * 101 * 4;

    // leaf (lw=5): h_child = 0, pairsum -> hA [65536][100]
    gru_level<false><<<2048, 512, 0, stream>>>(gio4, Wx3, Wh3, samp, addr,
                                               nullptr, hA, 5, 0);
    // L4: hA -> hB [32768][100]
    gru_level<true><<<1024, 512, LDSB, stream>>>(gio4, Wx3, Wh3, samp, addr, hA, hB, 4, 0);
    // L3: hB -> hA [16384][100]
    gru_level<true><<<512, 512, LDSB, stream>>>(gio4, Wx3, Wh3, samp, addr, hB, hA, 3, 0);
    // L2: hA -> hB [8192][100]
    gru_level<true><<<256, 512, LDSB, stream>>>(gio4, Wx3, Wh3, samp, addr, hA, hB, 2, 0);
    // L1: hB -> hA [4096][100]
    gru_level<true><<<128, 512, LDSB, stream>>>(gio4, Wx3, Wh3, samp, addr, hB, hA, 1, 0);
    // L0 (root, last): hA -> hB [4096][100]
    gru_level<true><<<64, 512, LDSB, stream>>>(gio4, Wx3, Wh3, samp, addr, hA, hB, 0, 1);

    mlp_lse<<<64, 64, 0, stream>>>(hB, W1T, b1, W2T, b2, W3, b3, out);
}

// Round 6
// 249.255 us; speedup vs baseline: 3.8525x; 3.0129x over previous
//
#include <hip/hip_runtime.h>
#include <hip/hip_bf16.h>

typedef __attribute__((ext_vector_type(8))) short bf16x8;
typedef __attribute__((ext_vector_type(4))) float f32x4;

__device__ __forceinline__ float sigmoidf_(float x){ return 1.0f/(1.0f+__expf(-x)); }
__device__ __forceinline__ float tanhf_(float x){ return 1.0f - 2.0f/(1.0f+__expf(2.0f*x)); }
__device__ __forceinline__ unsigned short f2bf(float f){
    __hip_bfloat16 b = __float2bfloat16(f);
    return *reinterpret_cast<unsigned short*>(&b);
}
__device__ __forceinline__ float bf2f(unsigned short u){
    __hip_bfloat16 b = *reinterpret_cast<__hip_bfloat16*>(&u);
    return __bfloat162float(b);
}
__device__ __forceinline__ void store_hl(unsigned short* hi, unsigned short* lo,
                                         size_t idx, float v){
    unsigned short h = f2bf(v);
    hi[idx] = h;
    lo[idx] = f2bf(v - bf2f(h));
}

// ---------------------------------------------------------------------------
// Layouts:
//  gio[o][448]: col c = region*112+u; region 0=r,1=z,2=i_n,3=h_n.
//    r/z: b_ih+b_hh+obs.W_ih[:, :100]; i_n: b_ih+obs part; h_n: b_hh. (0 for u>=100)
//  Bg (ushort): [ks 0..4][plane hi/lo][336 cols][40 k] ; 80B per col unit
//    (32 real k + 8 pad). ks0 = X rows (k=W_ih[:,100+kk], kk<18), slots 0..20 =
//    tiles 0..20 (regions r,z,in). ks>=1 = H rows (kh=(ks-1)*32+kk<100),
//    slots 0..13 = tiles 0..13 (r,z), slots 14..20 = tiles 21..27 (hn).
//  h planes (ushort): [rows][128], cols 0..99 = h (hi/lo split), 100..127 = 0.
// ---------------------------------------------------------------------------
__global__ __launch_bounds__(64) void precompute_kernel(
    const float* __restrict__ obs, const float* __restrict__ W_ih,
    const float* __restrict__ W_hh, const float* __restrict__ b_ih,
    const float* __restrict__ b_hh, const float* __restrict__ W1,
    const float* __restrict__ W2,
    float* __restrict__ gio, unsigned short* __restrict__ Bg,
    float* __restrict__ W1T, float* __restrict__ W2T)
{
    int t = blockIdx.x * 64 + threadIdx.x;
    if (t < 28672) { // gio
        int o = t / 448, c = t % 448;
        int region = c / 112, u = c % 112;
        float v = 0.f;
        if (u < 100) {
            if (region == 3) {
                v = b_hh[200 + u];
            } else {
                int gate = region * 100 + u;
                v = b_ih[gate] + (region < 2 ? b_hh[gate] : 0.f);
                const float* orow = obs + o * 100;
                const float* wrow = W_ih + (size_t)gate * 118;
                for (int k = 0; k < 100; ++k) v = fmaf(orow[k], wrow[k], v);
            }
        }
        gio[t] = v;
        return;
    }
    t -= 28672;
    if (t < 67200) { // Bg: one thread per (ks, slot, j, kk)
        int ks = t / 13440, r = t % 13440;
        int s = r / 640, r2 = r % 640;
        int j = r2 / 40, kk = r2 % 40;
        int tt = (ks == 0) ? s : (s < 14 ? s : s + 7);
        int region = tt / 7;
        int u = (tt % 7) * 16 + j;
        float wv = 0.f;
        if (u < 100 && kk < 32) {
            int gate = (region == 0) ? u : (region == 1 ? 100 + u : 200 + u);
            if (ks == 0) {
                if (kk < 18) wv = W_ih[(size_t)gate * 118 + 100 + kk];
            } else {
                int kh = (ks - 1) * 32 + kk;
                if (kh < 100) wv = W_hh[(size_t)gate * 100 + kh];
            }
        }
        unsigned short h = f2bf(wv);
        unsigned short l = f2bf(wv - bf2f(h));
        size_t base = (size_t)ks * 26880 + (size_t)(s * 16 + j) * 40 + kk;
        Bg[base] = h;
        Bg[base + 13440] = l;
        return;
    }
    t -= 67200;
    if (t < 5000) { int g = t / 50, j = t % 50; W1T[t] = W1[j * 100 + g]; return; }
    t -= 5000;
    if (t < 1250) { int j = t / 25, i = t % 25; W2T[t] = W2[i * 50 + j]; }
}

// ---------------------------------------------------------------------------
// GRU level via MFMA. Block = 256 thr = 4 waves; wave = one 16-cell M-tile.
// acc[28] f32x4: tiles 0-6=r, 7-13=z, 14-20=i_n, 21-27=h_n (units u=16t'+col).
// MFMA 16x16x32 bf16: A row=lane&15, k=(lane>>4)*8+j; B col=lane&15, same k;
// D col=lane&15, row=(lane>>4)*4+reg.  Split: D += Ahi*Bhi + Alo*Bhi + Ahi*Blo.
// ---------------------------------------------------------------------------
template<bool HASH>
__global__ __launch_bounds__(256) void gru_level(
    const float* __restrict__ gio,          // [64][448]
    const unsigned short* __restrict__ Bg,  // [5][2][336][40]
    const float* __restrict__ samp,         // (O,P,63,8)
    const float* __restrict__ addr,         // (O,P,63,10)
    const unsigned short* __restrict__ hinhi, // [cellsIn][128]
    const unsigned short* __restrict__ hinlo,
    unsigned short* __restrict__ houthi,    // [rowsOut][128]
    unsigned short* __restrict__ houtlo,
    int lw, int last)
{
    extern __shared__ unsigned short Blds[]; // 26880 ushorts = 53760 B = 3360 float4

    const int tid = threadIdx.x;
    const int lane = tid & 63;
    const int wid = tid >> 6;
    const int j15 = lane & 15;
    const int qr = lane >> 4;
    const int c0 = blockIdx.x * 64;
    const int c0w = c0 + wid * 16;
    const int o = c0 >> (lw + 6);           // uniform per block

    // ---- acc init from gio (bias + obs contributions) ----
    const float* grow = gio + o * 448;
    f32x4 acc[28];
    #pragma unroll
    for (int t = 0; t < 28; ++t) {
        float g = grow[t * 16 + j15];
        acc[t] = (f32x4){g, g, g, g};
    }

    // ---- build X A-frag in-register (row = c0w + j15, k-range per quarter) ----
    const int w = 1 << lw;
    const int cm = c0w + j15;
    const int opm = cm >> lw;
    const int nodem = w - 1 + (cm & (w - 1));
    const size_t nb = (size_t)opm * 63 + nodem;
    float xv0=0.f,xv1=0.f,xv2=0.f,xv3=0.f,xv4=0.f,xv5=0.f,xv6=0.f,xv7=0.f;
    if (qr == 0) {
        const float4* s4 = (const float4*)(samp + nb * 8);
        float4 a = s4[0], b = s4[1];
        xv0=a.x; xv1=a.y; xv2=a.z; xv3=a.w; xv4=b.x; xv5=b.y; xv6=b.z; xv7=b.w;
    } else if (qr == 1) {
        const float2* a2 = (const float2*)(addr + nb * 10);
        float2 e0=a2[0], e1=a2[1], e2=a2[2], e3=a2[3];
        xv0=e0.x; xv1=e0.y; xv2=e1.x; xv3=e1.y; xv4=e2.x; xv5=e2.y; xv6=e3.x; xv7=e3.y;
    } else if (qr == 2) {
        xv0 = addr[nb * 10 + 8]; xv1 = addr[nb * 10 + 9];
    }
    bf16x8 axhi, axlo;
    #define CVT(e, val) { unsigned short hh = f2bf(val); \
        axhi[e] = (short)hh; axlo[e] = (short)f2bf((val) - bf2f(hh)); }
    CVT(0, xv0) CVT(1, xv1) CVT(2, xv2) CVT(3, xv3)
    CVT(4, xv4) CVT(5, xv5) CVT(6, xv6) CVT(7, xv7)
    #undef CVT

    // ---- kstep 0: X GEMM (tiles 0..20 <- slots 0..20) ----
    {
        const float4* src = (const float4*)Bg;
        float4* dst = (float4*)Blds;
        for (int i = tid; i < 3360; i += 256) dst[i] = src[i];   // hi + lo planes
        __syncthreads();
        #pragma unroll
        for (int s = 0; s < 21; ++s) {
            const unsigned short* bb = Blds + (s * 16 + j15) * 40 + qr * 8;
            bf16x8 bhi = *(const bf16x8*)bb;
            bf16x8 blo = *(const bf16x8*)(bb + 13440);
            acc[s] = __builtin_amdgcn_mfma_f32_16x16x32_bf16(axhi, bhi, acc[s], 0, 0, 0);
            acc[s] = __builtin_amdgcn_mfma_f32_16x16x32_bf16(axlo, bhi, acc[s], 0, 0, 0);
            acc[s] = __builtin_amdgcn_mfma_f32_16x16x32_bf16(axhi, blo, acc[s], 0, 0, 0);
        }
    }

    // ---- ksteps 1..4: H GEMM (tiles 0..13 and 21..27) ----
    if constexpr (HASH) {
        for (int ks = 1; ks <= 4; ++ks) {
            __syncthreads();
            const float4* src = (const float4*)(Bg + (size_t)ks * 26880);
            float4* dst = (float4*)Blds;
            for (int i = tid; i < 3360; i += 256) dst[i] = src[i];  // hi + lo planes
            __syncthreads();
            const size_t abase = (size_t)(c0w + j15) * 128 + (ks - 1) * 32 + qr * 8;
            bf16x8 ahi = *(const bf16x8*)(hinhi + abase);
            bf16x8 alo = *(const bf16x8*)(hinlo + abase);
            #pragma unroll
            for (int s = 0; s < 14; ++s) {
                const unsigned short* bb = Blds + (s * 16 + j15) * 40 + qr * 8;
                bf16x8 bhi = *(const bf16x8*)bb;
                bf16x8 blo = *(const bf16x8*)(bb + 13440);
                acc[s] = __builtin_amdgcn_mfma_f32_16x16x32_bf16(ahi, bhi, acc[s], 0, 0, 0);
                acc[s] = __builtin_amdgcn_mfma_f32_16x16x32_bf16(alo, bhi, acc[s], 0, 0, 0);
                acc[s] = __builtin_amdgcn_mfma_f32_16x16x32_bf16(ahi, blo, acc[s], 0, 0, 0);
            }
            #pragma unroll
            for (int s = 14; s < 21; ++s) {
                const unsigned short* bb = Blds + (s * 16 + j15) * 40 + qr * 8;
                bf16x8 bhi = *(const bf16x8*)bb;
                bf16x8 blo = *(const bf16x8*)(bb + 13440);
                acc[s + 7] = __builtin_amdgcn_mfma_f32_16x16x32_bf16(ahi, bhi, acc[s + 7], 0, 0, 0);
                acc[s + 7] = __builtin_amdgcn_mfma_f32_16x16x32_bf16(alo, bhi, acc[s + 7], 0, 0, 0);
                acc[s + 7] = __builtin_amdgcn_mfma_f32_16x16x32_bf16(ahi, blo, acc[s + 7], 0, 0, 0);
            }
        }
    }

    // ---- epilogue: gates, pair-sum (regs are consecutive rows), store hi/lo ----
    #pragma unroll
    for (int t = 0; t < 7; ++t) {
        const int u = t * 16 + j15;
        float hv0, hv1, hv2, hv3;
        #define GATE(reg, hvout) { \
            float rr = sigmoidf_(acc[t][reg]); \
            float zz = sigmoidf_(acc[t + 7][reg]); \
            float nn = tanhf_(acc[t + 14][reg] + rr * acc[t + 21][reg]); \
            float hcv = 0.f; \
            if constexpr (HASH) { \
                size_t ii = (size_t)(c0w + qr * 4 + reg) * 128 + u; \
                hcv = bf2f(hinhi[ii]) + bf2f(hinlo[ii]); \
            } \
            hvout = (1.f - zz) * nn + zz * hcv; }
        GATE(0, hv0) GATE(1, hv1) GATE(2, hv2) GATE(3, hv3)
        #undef GATE
        if (last) {
            size_t r0 = (size_t)(c0w + qr * 4) * 128 + u;
            store_hl(houthi, houtlo, r0,       hv0);
            store_hl(houthi, houtlo, r0 + 128, hv1);
            store_hl(houthi, houtlo, r0 + 256, hv2);
            store_hl(houthi, houtlo, r0 + 384, hv3);
        } else {
            size_t r0 = (size_t)((c0w >> 1) + qr * 2) * 128 + u;
            store_hl(houthi, houtlo, r0,       hv0 + hv1);
            store_hl(houthi, houtlo, r0 + 128, hv2 + hv3);
        }
    }
    // zero k-padding cols 112..127 for the next level's A reads
    {
        const int u2 = 112 + j15;
        if (last) {
            #pragma unroll
            for (int reg = 0; reg < 4; ++reg) {
                size_t ii = (size_t)(c0w + qr * 4 + reg) * 128 + u2;
                houthi[ii] = 0; houtlo[ii] = 0;
            }
        } else {
            #pragma unroll
            for (int p = 0; p < 2; ++p) {
                size_t ii = (size_t)((c0w >> 1) + qr * 2 + p) * 128 + u2;
                houthi[ii] = 0; houtlo[ii] = 0;
            }
        }
    }
}

// ---------------------------------------------------------------------------
// MLP head + logsumexp over 64 particles. Block = one o; lane = particle.
// ---------------------------------------------------------------------------
__global__ __launch_bounds__(64) void mlp_lse(
    const unsigned short* __restrict__ h0hi, // [4096][128]
    const unsigned short* __restrict__ h0lo,
    const float* __restrict__ W1T,  // [100][50]
    const float* __restrict__ b1,
    const float* __restrict__ W2T,  // [50][25]
    const float* __restrict__ b2,
    const float* __restrict__ W3,
    const float* __restrict__ b3,
    float* __restrict__ out)
{
    __shared__ float hs[64 * 101];
    const int o = blockIdx.x;
    const int p = threadIdx.x;
    for (int f = p; f < 6400; f += 64) {
        int cl = f / 100, g = f - cl * 100;
        size_t idx = (size_t)(o * 64 + cl) * 128 + g;
        hs[cl * 101 + g] = bf2f(h0hi[idx]) + bf2f(h0lo[idx]);
    }
    __syncthreads();

    float y1[50];
    #pragma unroll
    for (int j = 0; j < 50; ++j) y1[j] = b1[j];
    #pragma unroll 2
    for (int g = 0; g < 100; ++g) {
        float rg = hs[p * 101 + g];
        const float* wr = W1T + g * 50;
        #pragma unroll
        for (int j = 0; j < 50; ++j) y1[j] = fmaf(rg, wr[j], y1[j]);
    }

    float y2[25];
    #pragma unroll
    for (int i = 0; i < 25; ++i) y2[i] = b2[i];
    #pragma unroll
    for (int j = 0; j < 50; ++j) {
        float v = fmaxf(y1[j], 0.0f);
        const float* wr = W2T + j * 25;
        #pragma unroll
        for (int i = 0; i < 25; ++i) y2[i] = fmaf(v, wr[i], y2[i]);
    }

    float cv = b3[0];
    #pragma unroll
    for (int i = 0; i < 25; ++i) cv = fmaf(fmaxf(y2[i], 0.0f), W3[i], cv);

    float m = cv;
    #pragma unroll
    for (int s = 1; s < 64; s <<= 1) m = fmaxf(m, __shfl_xor(m, s));
    float e = __expf(cv - m);
    #pragma unroll
    for (int s = 1; s < 64; s <<= 1) e += __shfl_xor(e, s);
    if (p == 0) out[o] = m + __logf(e) - 4.1588830833596715f; // log(64)
}

// ---------------------------------------------------------------------------
extern "C" void kernel_launch(void* const* d_in, const int* in_sizes, int n_in,
                              void* d_out, int out_size, void* d_ws, size_t ws_size,
                              hipStream_t stream)
{
    const float* obs  = (const float*)d_in[0];
    const float* samp = (const float*)d_in[1];
    const float* addr = (const float*)d_in[2];
    const float* W_ih = (const float*)d_in[3];
    const float* W_hh = (const float*)d_in[4];
    const float* b_ih = (const float*)d_in[5];
    const float* b_hh = (const float*)d_in[6];
    const float* W1   = (const float*)d_in[7];
    const float* b1   = (const float*)d_in[8];
    const float* W2   = (const float*)d_in[9];
    const float* b2   = (const float*)d_in[10];
    const float* W3   = (const float*)d_in[11];
    const float* b3   = (const float*)d_in[12];
    float* out = (float*)d_out;

    float* ws = (float*)d_ws;
    float* gio = ws;                                    // 28672 floats
    unsigned short* Bg = (unsigned short*)(ws + 28672); // 134400 ush = 67200 f
    float* W1T = ws + 95872;                            // 5000
    float* W2T = ws + 100872;                           // 1250
    // h planes (ushort), [rows][128]:
    unsigned short* hAhi = (unsigned short*)(ws + 102400);   // 65536*128 ush
    unsigned short* hAlo = (unsigned short*)(ws + 4296704);  // 65536*128 ush
    unsigned short* hBhi = (unsigned short*)(ws + 8491008);  // 32768*128 ush
    unsigned short* hBlo = (unsigned short*)(ws + 10588160); // 32768*128 ush

    precompute_kernel<<<(102122 + 63) / 64, 64, 0, stream>>>(
        obs, W_ih, W_hh, b_ih, b_hh, W1, W2, gio, Bg, W1T, W2T);

    const int LDSB = 26880 * 2; // 53760 B

    // leaf lw=5: 131072 cells -> pairsum 65536 rows (hA)
    gru_level<false><<<2048, 256, LDSB, stream>>>(gio, Bg, samp, addr,
        nullptr, nullptr, hAhi, hAlo, 5, 0);
    // L4: 65536 cells (hA) -> 32768 (hB)
    gru_level<true><<<1024, 256, LDSB, stream>>>(gio, Bg, samp, addr,
        hAhi, hAlo, hBhi, hBlo, 4, 0);
    // L3: 32768 (hB) -> 16384 (hA)
    gru_level<true><<<512, 256, LDSB, stream>>>(gio, Bg, samp, addr,
        hBhi, hBlo, hAhi, hAlo, 3, 0);
    // L2: 16384 (hA) -> 8192 (hB)
    gru_level<true><<<256, 256, LDSB, stream>>>(gio, Bg, samp, addr,
        hAhi, hAlo, hBhi, hBlo, 2, 0);
    // L1: 8192 (hB) -> 4096 (hA)
    gru_level<true><<<128, 256, LDSB, stream>>>(gio, Bg, samp, addr,
        hBhi, hBlo, hAhi, hAlo, 1, 0);
    // L0 (root, last): 4096 (hA) -> 4096 (hB)
    gru_level<true><<<64, 256, LDSB, stream>>>(gio, Bg, samp, addr,
        hAhi, hAlo, hBhi, hBlo, 0, 1);

    mlp_lse<<<64, 64, 0, stream>>>(hBhi, hBlo, W1T, b1, W2T, b2, W3, b3, out);
}

// Round 9
// 219.208 us; speedup vs baseline: 4.3805x; 1.1371x over previous
//
#include <hip/hip_runtime.h>
#include <hip/hip_bf16.h>

typedef __attribute__((ext_vector_type(8))) short bf16x8;
typedef __attribute__((ext_vector_type(4))) float f32x4;

__device__ __forceinline__ float sigmoidf_(float x){ return 1.0f/(1.0f+__expf(-x)); }
__device__ __forceinline__ float tanhf_(float x){ return 1.0f - 2.0f/(1.0f+__expf(2.0f*x)); }
__device__ __forceinline__ unsigned short f2bf(float f){
    __hip_bfloat16 b = __float2bfloat16(f);
    return *reinterpret_cast<unsigned short*>(&b);
}
__device__ __forceinline__ float bf2f(unsigned short u){
    __hip_bfloat16 b = *reinterpret_cast<__hip_bfloat16*>(&u);
    return __bfloat162float(b);
}
__device__ __forceinline__ void store_hl(unsigned short* hi, unsigned short* lo,
                                         size_t idx, float v){
    unsigned short h = f2bf(v);
    hi[idx] = h;
    lo[idx] = f2bf(v - bf2f(h));
}

// ---------------------------------------------------------------------------
// Layouts:
//  gio[o][448]: col c = region*112+u; region 0=r,1=z,2=i_n,3=h_n.
//  Bg (ushort): per kstep slab 21504 ush = [plane hi/lo][21 slots][4 qr][16 j][8 e]
//    -> a wave's (qr,j15) b128 read of one slot touches 64 consecutive 16B
//       chunks = conflict-free. plane stride 10752 ush, slab stride 21504 ush.
//    ks0 = X rows (kk<18 of W_ih[:,100+kk]); slots 0..20 = tiles 0..20 (r,z,in).
//    ks>=1 = H rows (kh=(ks-1)*32+kk<100); slots 0..13 -> tiles 0..13 (r,z),
//    slots 14..20 -> tiles 21..27 (hn).  REGION 3 (hn) USES GATE ROWS 200+u
//    (same n-gate rows as region 2) — NOT 300+u!
//  h planes (ushort): [rows][128], cols 0..99 = h (hi/lo split), 100..127 = 0.
// ---------------------------------------------------------------------------
__global__ __launch_bounds__(64) void precompute_kernel(
    const float* __restrict__ obs, const float* __restrict__ W_ih,
    const float* __restrict__ W_hh, const float* __restrict__ b_ih,
    const float* __restrict__ b_hh, const float* __restrict__ W1,
    const float* __restrict__ W2,
    float* __restrict__ gio, unsigned short* __restrict__ Bg,
    float* __restrict__ W1T, float* __restrict__ W2T)
{
    int t = blockIdx.x * 64 + threadIdx.x;
    if (t < 28672) { // gio
        int o = t / 448, c = t % 448;
        int region = c / 112, u = c % 112;
        float v = 0.f;
        if (u < 100) {
            if (region == 3) {
                v = b_hh[200 + u];
            } else {
                int gate = region * 100 + u;
                v = b_ih[gate] + (region < 2 ? b_hh[gate] : 0.f);
                const float* orow = obs + o * 100;
                const float* wrow = W_ih + (size_t)gate * 118;
                for (int k = 0; k < 100; ++k) v = fmaf(orow[k], wrow[k], v);
            }
        }
        gio[t] = v;
        return;
    }
    t -= 28672;
    if (t < 53760) { // Bg: one thread per (ks, slot, j, kk)
        int ks = t / 10752, r = t % 10752;
        int s = r / 512, r2 = r % 512;
        int j = r2 / 32, kk = r2 % 32;
        int tt = (ks == 0) ? s : (s < 14 ? s : s + 7);
        int region = tt / 7;
        int u = (tt % 7) * 16 + j;
        float wv = 0.f;
        if (u < 100) {
            // region 3 (h_n) uses the SAME n-gate rows (200+u) as region 2 (i_n)
            int gate = (region == 3 ? 2 : region) * 100 + u;
            if (ks == 0) {
                if (kk < 18) wv = W_ih[(size_t)gate * 118 + 100 + kk];
            } else {
                int kh = (ks - 1) * 32 + kk;
                if (kh < 100) wv = W_hh[(size_t)gate * 100 + kh];
            }
        }
        unsigned short h = f2bf(wv);
        unsigned short l = f2bf(wv - bf2f(h));
        int qr = kk >> 3, e = kk & 7;
        size_t base = (size_t)ks * 21504 + (size_t)((s * 4 + qr) * 16 + j) * 8 + e;
        Bg[base] = h;
        Bg[base + 10752] = l;
        return;
    }
    t -= 53760;
    if (t < 5000) { int g = t / 50, j = t % 50; W1T[t] = W1[j * 100 + g]; return; }
    t -= 5000;
    if (t < 1250) { int j = t / 25, i = t % 25; W2T[t] = W2[i * 50 + j]; }
}

// ---------------------------------------------------------------------------
// GRU level via MFMA. Block = NW waves; wave = one 16-cell M-tile.
// acc[28] f32x4: tiles 0-6=r, 7-13=z, 14-20=i_n, 21-27=h_n (units u=16t'+col).
// B slab staged per kstep in LDS (conflict-free layout); H A-frags prefetched
// at kernel start; split-bf16: D += Ahi*Bhi + Alo*Bhi + Ahi*Blo.
// ---------------------------------------------------------------------------
template<bool HASH, int NW>
__global__ __launch_bounds__(NW * 64) void gru_level(
    const float* __restrict__ gio,          // [64][448]
    const unsigned short* __restrict__ Bg,  // [5][2][21][4][16][8]
    const float* __restrict__ samp,         // (O,P,63,8)
    const float* __restrict__ addr,         // (O,P,63,10)
    const unsigned short* __restrict__ hinhi, // [cellsIn][128]
    const unsigned short* __restrict__ hinlo,
    unsigned short* __restrict__ houthi,    // [rowsOut][128]
    unsigned short* __restrict__ houtlo,
    int lw, int last)
{
    __shared__ unsigned short Blds[21504];  // 43008 B = 2688 float4 (hi+lo planes!)

    const int tid = threadIdx.x;
    const int lane = tid & 63;
    const int wid = tid >> 6;
    const int j15 = lane & 15;
    const int qr = lane >> 4;
    const int c0 = blockIdx.x * (NW * 16);
    const int c0w = c0 + wid * 16;
    const int o = c0w >> (lw + 6);          // uniform per wave

    // ---- prefetch all H A-fragments (issued once, consumed across ksteps) ----
    bf16x8 ahi[4], alo[4];
    if constexpr (HASH) {
        const size_t arow = (size_t)(c0w + j15) * 128 + qr * 8;
        #pragma unroll
        for (int m = 0; m < 4; ++m) {
            ahi[m] = *(const bf16x8*)(hinhi + arow + m * 32);
            alo[m] = *(const bf16x8*)(hinlo + arow + m * 32);
        }
    }

    // ---- acc init from gio (bias + obs contributions) ----
    const float* grow = gio + o * 448;
    f32x4 acc[28];
    #pragma unroll
    for (int t = 0; t < 28; ++t) {
        float g = grow[t * 16 + j15];
        acc[t] = (f32x4){g, g, g, g};
    }

    // ---- build X A-frag in-register (row = c0w + j15, k slice per quarter) ----
    const int w = 1 << lw;
    const int cm = c0w + j15;
    const int opm = cm >> lw;
    const int nodem = w - 1 + (cm & (w - 1));
    const size_t nb = (size_t)opm * 63 + nodem;
    float xv0=0.f,xv1=0.f,xv2=0.f,xv3=0.f,xv4=0.f,xv5=0.f,xv6=0.f,xv7=0.f;
    if (qr == 0) {
        const float4* s4 = (const float4*)(samp + nb * 8);
        float4 a = s4[0], b = s4[1];
        xv0=a.x; xv1=a.y; xv2=a.z; xv3=a.w; xv4=b.x; xv5=b.y; xv6=b.z; xv7=b.w;
    } else if (qr == 1) {
        const float2* a2 = (const float2*)(addr + nb * 10);
        float2 e0=a2[0], e1=a2[1], e2=a2[2], e3=a2[3];
        xv0=e0.x; xv1=e0.y; xv2=e1.x; xv3=e1.y; xv4=e2.x; xv5=e2.y; xv6=e3.x; xv7=e3.y;
    } else if (qr == 2) {
        xv0 = addr[nb * 10 + 8]; xv1 = addr[nb * 10 + 9];
    }
    bf16x8 axhi, axlo;
    #define CVT(e, val) { unsigned short hh = f2bf(val); \
        axhi[e] = (short)hh; axlo[e] = (short)f2bf((val) - bf2f(hh)); }
    CVT(0, xv0) CVT(1, xv1) CVT(2, xv2) CVT(3, xv3)
    CVT(4, xv4) CVT(5, xv5) CVT(6, xv6) CVT(7, xv7)
    #undef CVT

    // ---- kstep loop: stage slab -> barrier -> MFMA ----
    #pragma unroll
    for (int ks = 0; ks <= (HASH ? 4 : 0); ++ks) {
        if (ks) __syncthreads();            // protect slab overwrite
        {
            // slab = 21504 ushorts * 2 B / 16 B = 2688 float4 (hi AND lo planes)
            const float4* src = (const float4*)(Bg + (size_t)ks * 21504);
            float4* dst = (float4*)Blds;
            #pragma unroll
            for (int i = tid; i < 2688; i += NW * 64) dst[i] = src[i];
        }
        __syncthreads();

        if (ks == 0) {
            #pragma unroll
            for (int s = 0; s < 21; ++s) {
                const unsigned short* bb = Blds + ((s * 4 + qr) * 16 + j15) * 8;
                bf16x8 bhi = *(const bf16x8*)bb;
                bf16x8 blo = *(const bf16x8*)(bb + 10752);
                acc[s] = __builtin_amdgcn_mfma_f32_16x16x32_bf16(axhi, bhi, acc[s], 0, 0, 0);
                acc[s] = __builtin_amdgcn_mfma_f32_16x16x32_bf16(axlo, bhi, acc[s], 0, 0, 0);
                acc[s] = __builtin_amdgcn_mfma_f32_16x16x32_bf16(axhi, blo, acc[s], 0, 0, 0);
            }
        } else if constexpr (HASH) {
            const int m = ks - 1;
            #pragma unroll
            for (int s = 0; s < 21; ++s) {
                const int d = (s < 14) ? s : s + 7;
                const unsigned short* bb = Blds + ((s * 4 + qr) * 16 + j15) * 8;
                bf16x8 bhi = *(const bf16x8*)bb;
                bf16x8 blo = *(const bf16x8*)(bb + 10752);
                acc[d] = __builtin_amdgcn_mfma_f32_16x16x32_bf16(ahi[m], bhi, acc[d], 0, 0, 0);
                acc[d] = __builtin_amdgcn_mfma_f32_16x16x32_bf16(alo[m], bhi, acc[d], 0, 0, 0);
                acc[d] = __builtin_amdgcn_mfma_f32_16x16x32_bf16(ahi[m], blo, acc[d], 0, 0, 0);
            }
        }
    }

    // ---- epilogue: gates, pair-sum (regs are consecutive rows), store hi/lo ----
    #pragma unroll
    for (int t = 0; t < 7; ++t) {
        const int u = t * 16 + j15;
        float hv0, hv1, hv2, hv3;
        #define GATE(reg, hvout) { \
            float rr = sigmoidf_(acc[t][reg]); \
            float zz = sigmoidf_(acc[t + 7][reg]); \
            float nn = tanhf_(acc[t + 14][reg] + rr * acc[t + 21][reg]); \
            float hcv = 0.f; \
            if constexpr (HASH) { \
                size_t ii = (size_t)(c0w + qr * 4 + reg) * 128 + u; \
                hcv = bf2f(hinhi[ii]) + bf2f(hinlo[ii]); \
            } \
            hvout = (1.f - zz) * nn + zz * hcv; }
        GATE(0, hv0) GATE(1, hv1) GATE(2, hv2) GATE(3, hv3)
        #undef GATE
        if (last) {
            size_t r0 = (size_t)(c0w + qr * 4) * 128 + u;
            store_hl(houthi, houtlo, r0,       hv0);
            store_hl(houthi, houtlo, r0 + 128, hv1);
            store_hl(houthi, houtlo, r0 + 256, hv2);
            store_hl(houthi, houtlo, r0 + 384, hv3);
        } else {
            size_t r0 = (size_t)((c0w >> 1) + qr * 2) * 128 + u;
            store_hl(houthi, houtlo, r0,       hv0 + hv1);
            store_hl(houthi, houtlo, r0 + 128, hv2 + hv3);
        }
    }
    // zero k-padding cols 112..127 for the next level's A reads
    {
        const int u2 = 112 + j15;
        if (last) {
            #pragma unroll
            for (int reg = 0; reg < 4; ++reg) {
                size_t ii = (size_t)(c0w + qr * 4 + reg) * 128 + u2;
                houthi[ii] = 0; houtlo[ii] = 0;
            }
        } else {
            #pragma unroll
            for (int p = 0; p < 2; ++p) {
                size_t ii = (size_t)((c0w >> 1) + qr * 2 + p) * 128 + u2;
                houthi[ii] = 0; houtlo[ii] = 0;
            }
        }
    }
}

// ---------------------------------------------------------------------------
// MLP head + logsumexp over 64 particles. Block = one o; lane = particle.
// ---------------------------------------------------------------------------
__global__ __launch_bounds__(64) void mlp_lse(
    const unsigned short* __restrict__ h0hi, // [4096][128]
    const unsigned short* __restrict__ h0lo,
    const float* __restrict__ W1T,  // [100][50]
    const float* __restrict__ b1,
    const float* __restrict__ W2T,  // [50][25]
    const float* __restrict__ b2,
    const float* __restrict__ W3,
    const float* __restrict__ b3,
    float* __restrict__ out)
{
    __shared__ float hs[64 * 101];
    const int o = blockIdx.x;
    const int p = threadIdx.x;
    for (int f = p; f < 6400; f += 64) {
        int cl = f / 100, g = f - cl * 100;
        size_t idx = (size_t)(o * 64 + cl) * 128 + g;
        hs[cl * 101 + g] = bf2f(h0hi[idx]) + bf2f(h0lo[idx]);
    }
    __syncthreads();

    float y1[50];
    #pragma unroll
    for (int j = 0; j < 50; ++j) y1[j] = b1[j];
    #pragma unroll 2
    for (int g = 0; g < 100; ++g) {
        float rg = hs[p * 101 + g];
        const float* wr = W1T + g * 50;
        #pragma unroll
        for (int j = 0; j < 50; ++j) y1[j] = fmaf(rg, wr[j], y1[j]);
    }

    float y2[25];
    #pragma unroll
    for (int i = 0; i < 25; ++i) y2[i] = b2[i];
    #pragma unroll
    for (int j = 0; j < 50; ++j) {
        float v = fmaxf(y1[j], 0.0f);
        const float* wr = W2T + j * 25;
        #pragma unroll
        for (int i = 0; i < 25; ++i) y2[i] = fmaf(v, wr[i], y2[i]);
    }

    float cv = b3[0];
    #pragma unroll
    for (int i = 0; i < 25; ++i) cv = fmaf(fmaxf(y2[i], 0.0f), W3[i], cv);

    float m = cv;
    #pragma unroll
    for (int s = 1; s < 64; s <<= 1) m = fmaxf(m, __shfl_xor(m, s));
    float e = __expf(cv - m);
    #pragma unroll
    for (int s = 1; s < 64; s <<= 1) e += __shfl_xor(e, s);
    if (p == 0) out[o] = m + __logf(e) - 4.1588830833596715f; // log(64)
}

// ---------------------------------------------------------------------------
extern "C" void kernel_launch(void* const* d_in, const int* in_sizes, int n_in,
                              void* d_out, int out_size, void* d_ws, size_t ws_size,
                              hipStream_t stream)
{
    const float* obs  = (const float*)d_in[0];
    const float* samp = (const float*)d_in[1];
    const float* addr = (const float*)d_in[2];
    const float* W_ih = (const float*)d_in[3];
    const float* W_hh = (const float*)d_in[4];
    const float* b_ih = (const float*)d_in[5];
    const float* b_hh = (const float*)d_in[6];
    const float* W1   = (const float*)d_in[7];
    const float* b1   = (const float*)d_in[8];
    const float* W2   = (const float*)d_in[9];
    const float* b2   = (const float*)d_in[10];
    const float* W3   = (const float*)d_in[11];
    const float* b3   = (const float*)d_in[12];
    float* out = (float*)d_out;

    float* ws = (float*)d_ws;
    float* gio = ws;                                     // 28672 floats
    unsigned short* Bg = (unsigned short*)(ws + 28672);  // 107520 ush = 53760 f
    float* W1T = ws + 82432;                             // 5000
    float* W2T = ws + 87432;                             // 1250
    // h planes (ushort), [rows][128]:
    unsigned short* hAhi = (unsigned short*)(ws + 90112);    // 65536*128 ush = 4194304 f
    unsigned short* hAlo = (unsigned short*)(ws + 4284416);  // 65536*128 ush
    unsigned short* hBhi = (unsigned short*)(ws + 8478720);  // 32768*128 ush = 2097152 f
    unsigned short* hBlo = (unsigned short*)(ws + 10575872); // 32768*128 ush

    precompute_kernel<<<(88682 + 63) / 64, 64, 0, stream>>>(
        obs, W_ih, W_hh, b_ih, b_hh, W1, W2, gio, Bg, W1T, W2T);

    // leaf lw=5: 131072 cells -> pairsum 65536 rows (hA)
    gru_level<false, 8><<<1024, 512, 0, stream>>>(gio, Bg, samp, addr,
        nullptr, nullptr, hAhi, hAlo, 5, 0);
    // L4: 65536 cells (hA) -> 32768 (hB)
    gru_level<true, 8><<<512, 512, 0, stream>>>(gio, Bg, samp, addr,
        hAhi, hAlo, hBhi, hBlo, 4, 0);
    // L3: 32768 (hB) -> 16384 (hA)
    gru_level<true, 8><<<256, 512, 0, stream>>>(gio, Bg, samp, addr,
        hBhi, hBlo, hAhi, hAlo, 3, 0);
    // L2: 16384 (hA) -> 8192 (hB)
    gru_level<true, 4><<<256, 256, 0, stream>>>(gio, Bg, samp, addr,
        hAhi, hAlo, hBhi, hBlo, 2, 0);
    // L1: 8192 (hB) -> 4096 (hA)
    gru_level<true, 4><<<128, 256, 0, stream>>>(gio, Bg, samp, addr,
        hBhi, hBlo, hAhi, hAlo, 1, 0);
    // L0 (root, last): 4096 (hA) -> 4096 (hB)
    gru_level<true, 4><<<64, 256, 0, stream>>>(gio, Bg, samp, addr,
        hAhi, hAlo, hBhi, hBlo, 0, 1);

    mlp_lse<<<64, 64, 0, stream>>>(hBhi, hBlo, W1T, b1, W2T, b2, W3, b3, out);
}